// Round 12
// baseline (593.407 us; speedup 1.0000x reference)
//
#include <hip/hip_runtime.h>

#define NN 100000
#define EE 1600000
#define DD 128
#define HH 128
#define LL 3
#define GG 512
#define LATENT 64
#define BN_EPS 1e-5f
#define SLOPE 0.2f
#define ASTR 136        // padded LDS row stride (ushorts); 272B = 17*16B (uint4-aligned)
#define NC (2 * NN)     // split counters: 2 per node
#define NB2 782         // ceil(NC/256)

typedef __attribute__((ext_vector_type(8))) short short8;
typedef __attribute__((ext_vector_type(4))) float floatx4;
typedef __attribute__((ext_vector_type(2))) float floatx2;

__device__ __forceinline__ float leaky(float t) { return t > 0.f ? t : SLOPE * t; }

__device__ __forceinline__ unsigned short f2bf(float x) {
    union { float f; unsigned int u; } v; v.f = x;
    unsigned int r = v.u + 0x7fffu + ((v.u >> 16) & 1u);
    return (unsigned short)(r >> 16);
}
__device__ __forceinline__ unsigned int pk2(float a, float b) {
    return (unsigned int)f2bf(a) | ((unsigned int)f2bf(b) << 16);
}
__device__ __forceinline__ float bf_lo(unsigned int p) {
    union { unsigned int u; float f; } v; v.u = p << 16; return v.f;
}
__device__ __forceinline__ float bf_hi(unsigned int p) {
    union { unsigned int u; float f; } v; v.u = p & 0xffff0000u; return v.f;
}
__device__ __forceinline__ floatx2 up2(unsigned int p) {
    union { unsigned int u; float f; } lo, hi;
    lo.u = p << 16; hi.u = p & 0xffff0000u;
    floatx2 r; r.x = lo.f; r.y = hi.f; return r;
}

// ---------------- merged: hist (split counters) + gstart + cvtW + cvtX ----------------
#define HIST_B 6250
#define PG 391
#define PW 48
#define PX 6250
#define HP_BLOCKS (HIST_B + PG + PW + PX)

__global__ __launch_bounds__(256) void histprep(const int* __restrict__ dst,
                                                int* __restrict__ deg2, int* __restrict__ rank,
                                                const int* __restrict__ batch, int* __restrict__ gstart,
                                                const float* __restrict__ W1, const float* __restrict__ W2,
                                                uint4* __restrict__ Wf,
                                                const float4* __restrict__ x4, uint4* __restrict__ hx4) {
    int b = blockIdx.x;
    int tid = threadIdx.x;
    if (b < HIST_B) {
        int e = b * 256 + tid;
        if (e < EE) rank[e] = atomicAdd(&deg2[(dst[e] << 1) | (e & 1)], 1);
        return;
    }
    b -= HIST_B;
    if (b < PG) {
        int n = b * 256 + tid;
        if (n >= NN) return;
        int bb = batch[n];
        int pb = (n == 0) ? -1 : batch[n - 1];
        for (int g = pb + 1; g <= bb; ++g) gstart[g] = n;
        if (n == NN - 1)
            for (int g = bb + 1; g <= GG; ++g) gstart[g] = NN;
        return;
    }
    b -= PG;
    if (b < PW) {
        int t = b * 256 + tid;  // 6*2048
        int mat = t >> 11;
        int idx = t & 2047;
        const float* W = ((mat & 1) ? W2 : W1) + (size_t)(mat >> 1) * 128 * 128;
        int lane = idx & 63;
        int tn = (idx >> 6) & 7;
        int kk = idx >> 9;
        int n = tn * 16 + (lane & 15);
        int kb = kk * 32 + (lane >> 4) * 8;
        unsigned int p[4];
#pragma unroll
        for (int jj = 0; jj < 4; ++jj)
            p[jj] = pk2(W[(kb + 2 * jj) * 128 + n], W[(kb + 2 * jj + 1) * 128 + n]);
        Wf[t] = make_uint4(p[0], p[1], p[2], p[3]);
        return;
    }
    b -= PW;
    int i = b * 256 + tid;  // uint4 index, NN*16 total
    if (i >= NN * 16) return;
    float4 p0 = x4[2 * i], p1 = x4[2 * i + 1];
    uint4 o;
    o.x = pk2(p0.x, p0.y);
    o.y = pk2(p0.z, p0.w);
    o.z = pk2(p1.x, p1.y);
    o.w = pk2(p1.z, p1.w);
    hx4[i] = o;
}

// ---------------- scan1: per-256-chunk sums of deg2 ----------------
__global__ __launch_bounds__(256) void scan1(const int* __restrict__ deg2, int* __restrict__ bsum) {
    __shared__ int lds[256];
    int n = blockIdx.x * 256 + threadIdx.x;
    lds[threadIdx.x] = (n < NC) ? deg2[n] : 0;
    __syncthreads();
    for (int off = 128; off > 0; off >>= 1) {
        if (threadIdx.x < off) lds[threadIdx.x] += lds[threadIdx.x + off];
        __syncthreads();
    }
    if (threadIdx.x == 0) bsum[blockIdx.x] = lds[0];
}

// ---------------- scan3f: block offset (reduce bsum[j<bid]) + local exclusive scan ----------------
__global__ __launch_bounds__(256) void scan3f(const int* __restrict__ deg2, const int* __restrict__ bsum,
                                              int* __restrict__ row_ptr2) {
    __shared__ int red[256];
    int tid = threadIdx.x;
    int bid = blockIdx.x;
    int acc = 0;
    for (int j = tid; j < bid; j += 256) acc += bsum[j];
    red[tid] = acc;
    __syncthreads();
    for (int off = 128; off > 0; off >>= 1) {
        if (tid < off) red[tid] += red[tid + off];
        __syncthreads();
    }
    int base = red[0];
    __syncthreads();
    int n = bid * 256 + tid;
    int v = (n < NC) ? deg2[n] : 0;
    red[tid] = v;
    __syncthreads();
    for (int off = 1; off < 256; off <<= 1) {
        int t = (tid >= off) ? red[tid - off] : 0;
        __syncthreads();
        red[tid] += t;
        __syncthreads();
    }
    if (n < NC) row_ptr2[n] = base + red[tid] - v;
    if (n == 0) row_ptr2[NC] = EE;
}

// ---------------- fill: atomic-free scatter ----------------
__global__ void fill2(const int* __restrict__ src, const int* __restrict__ dst,
                      const int* __restrict__ rank, const int* __restrict__ row_ptr2,
                      int* __restrict__ col) {
    int e = blockIdx.x * blockDim.x + threadIdx.x;
    if (e < EE) col[row_ptr2[(dst[e] << 1) | (e & 1)] + rank[e]] = src[e];
}

// ---------------- aggregation (bf16, 8 edge slots, 2 uint4/lane) ----------------
__global__ __launch_bounds__(256) void agg_bf16w8(const unsigned int* __restrict__ h,
                                                  const int* __restrict__ row_ptr2,
                                                  const int* __restrict__ col,
                                                  unsigned int* __restrict__ u) {
    int node = blockIdx.x * 4 + (threadIdx.x >> 6);
    int lane = threadIdx.x & 63;
    if (node >= NN) return;
    const int grp = lane >> 3;
    const int sub = lane & 7;
    const uint4* hv = (const uint4*)h;

    floatx2 a[8];
#pragma unroll
    for (int t = 0; t < 8; ++t) { a[t].x = 0.f; a[t].y = 0.f; }

    if (grp == 0) {
        uint4 v0 = hv[(size_t)node * 16 + sub];
        uint4 v1 = hv[(size_t)node * 16 + 8 + sub];
        a[0] += up2(v0.x); a[1] += up2(v0.y); a[2] += up2(v0.z); a[3] += up2(v0.w);
        a[4] += up2(v1.x); a[5] += up2(v1.y); a[6] += up2(v1.z); a[7] += up2(v1.w);
    }
    int s = row_ptr2[node << 1], e = row_ptr2[(node << 1) + 2];
    for (int j = s + grp; j < e; j += 8) {
        int c = col[j];
        uint4 v0 = hv[(size_t)c * 16 + sub];
        uint4 v1 = hv[(size_t)c * 16 + 8 + sub];
        a[0] += up2(v0.x); a[1] += up2(v0.y); a[2] += up2(v0.z); a[3] += up2(v0.w);
        a[4] += up2(v1.x); a[5] += up2(v1.y); a[6] += up2(v1.z); a[7] += up2(v1.w);
    }
#pragma unroll
    for (int t = 0; t < 8; ++t) {
        a[t].x += __shfl_xor(a[t].x, 8);
        a[t].y += __shfl_xor(a[t].y, 8);
        a[t].x += __shfl_xor(a[t].x, 16);
        a[t].y += __shfl_xor(a[t].y, 16);
        a[t].x += __shfl_xor(a[t].x, 32);
        a[t].y += __shfl_xor(a[t].y, 32);
    }
    if (grp == 0) {
        uint4 o0, o1;
        o0.x = pk2(a[0].x, a[0].y);
        o0.y = pk2(a[1].x, a[1].y);
        o0.z = pk2(a[2].x, a[2].y);
        o0.w = pk2(a[3].x, a[3].y);
        o1.x = pk2(a[4].x, a[4].y);
        o1.y = pk2(a[5].x, a[5].y);
        o1.z = pk2(a[6].x, a[6].y);
        o1.w = pk2(a[7].x, a[7].y);
        ((uint4*)u)[(size_t)node * 16 + sub] = o0;
        ((uint4*)u)[(size_t)node * 16 + 8 + sub] = o1;
    }
}

// ---------------- fused MLP: Out = leaky(BN(leaky(A@W1+b1))@W2 + b2) ----------------
// Single 34.8KB LDS buffer (staged A -> per-wave in-place mid -> output tile).
// NO min-waves pin: r11's __launch_bounds__(256,4) forced a 128-VGPR cap -> spills.
// Let the allocator pick; LDS allows up to 4 blocks/CU, VGPRs should give ~3.
__global__ __launch_bounds__(256) void mlp_fused(const unsigned short* __restrict__ A,
                                                 const uint4* __restrict__ W1f,
                                                 const uint4* __restrict__ W2f,
                                                 const float* __restrict__ b1,
                                                 const float* __restrict__ g,
                                                 const float* __restrict__ beta,
                                                 const float* __restrict__ rm,
                                                 const float* __restrict__ rv,
                                                 const float* __restrict__ b2,
                                                 unsigned short* __restrict__ Out) {
    __shared__ unsigned short aL[128 * ASTR];  // 34816 B
    const int tid = threadIdx.x;
    const int rb = blockIdx.x * 128;

    const uint4* Ag = (const uint4*)(A + (size_t)rb * 128);
#pragma unroll
    for (int it = 0; it < 8; ++it) {
        int idx = it * 256 + tid;
        int r = idx >> 4, c = idx & 15;
        uint4 v = make_uint4(0u, 0u, 0u, 0u);
        if (rb + r < NN) v = Ag[idx];
        *(uint4*)&aL[r * ASTR + c * 8] = v;
    }
    __syncthreads();

    const int wid = tid >> 6, lane = tid & 63;
    const int ml = lane & 15, q = lane >> 4;
    const int m0 = wid * 32;

    floatx4 acc[2][8] = {};
#pragma unroll
    for (int kk = 0; kk < 4; ++kk) {
        short8 af[2];
#pragma unroll
        for (int t = 0; t < 2; ++t)
            af[t] = *(const short8*)&aL[(m0 + t * 16 + ml) * ASTR + kk * 32 + q * 8];
#pragma unroll
        for (int tn = 0; tn < 8; ++tn) {
            uint4 bq = W1f[(kk * 8 + tn) * 64 + lane];
            short8 bf = *(short8*)&bq;
            acc[0][tn] = __builtin_amdgcn_mfma_f32_16x16x32_bf16(af[0], bf, acc[0][tn], 0, 0, 0);
            acc[1][tn] = __builtin_amdgcn_mfma_f32_16x16x32_bf16(af[1], bf, acc[1][tn], 0, 0, 0);
        }
    }

    // epilogue 1: bias + leaky + BN -> mid, in-place in this wave's aL rows (wave-private)
#pragma unroll
    for (int tn = 0; tn < 8; ++tn) {
        int c = tn * 16 + ml;
        float s = g[c] * rsqrtf(rv[c] + BN_EPS);
        float sh = beta[c] - s * rm[c];
        float bv = b1[c];
#pragma unroll
        for (int t = 0; t < 2; ++t)
#pragma unroll
            for (int r = 0; r < 4; ++r) {
                float val = leaky(acc[t][tn][r] + bv);
                val = s * val + sh;
                aL[(m0 + t * 16 + q * 4 + r) * ASTR + c] = f2bf(val);
            }
    }

    floatx4 acc2[2][8] = {};
#pragma unroll
    for (int kk = 0; kk < 4; ++kk) {
        short8 af[2];
#pragma unroll
        for (int t = 0; t < 2; ++t)
            af[t] = *(const short8*)&aL[(m0 + t * 16 + ml) * ASTR + kk * 32 + q * 8];
#pragma unroll
        for (int tn = 0; tn < 8; ++tn) {
            uint4 bq = W2f[(kk * 8 + tn) * 64 + lane];
            short8 bf = *(short8*)&bq;
            acc2[0][tn] = __builtin_amdgcn_mfma_f32_16x16x32_bf16(af[0], bf, acc2[0][tn], 0, 0, 0);
            acc2[1][tn] = __builtin_amdgcn_mfma_f32_16x16x32_bf16(af[1], bf, acc2[1][tn], 0, 0, 0);
        }
    }

    // epilogue 2: bias + leaky -> output tile, in-place in this wave's aL rows
#pragma unroll
    for (int tn = 0; tn < 8; ++tn) {
        int c = tn * 16 + ml;
        float bv = b2[c];
#pragma unroll
        for (int t = 0; t < 2; ++t)
#pragma unroll
            for (int r = 0; r < 4; ++r)
                aL[(m0 + t * 16 + q * 4 + r) * ASTR + c] = f2bf(leaky(acc2[t][tn][r] + bv));
    }
    __syncthreads();

    uint4* Og = (uint4*)(Out + (size_t)rb * 128);
#pragma unroll
    for (int it = 0; it < 8; ++it) {
        int idx = it * 256 + tid;
        int r = idx >> 4, c = idx & 15;
        if (rb + r < NN)
            Og[idx] = *(const uint4*)&aL[r * ASTR + c * 8];
    }
}

// ---------------- fused pooling + BN + final FC ----------------
__global__ __launch_bounds__(256) void poolfc(const unsigned int* __restrict__ h,
                                              const int* __restrict__ gstart,
                                              const float* __restrict__ bng,
                                              const float* __restrict__ bnb,
                                              const float* __restrict__ bnrm,
                                              const float* __restrict__ bnrv,
                                              const float* __restrict__ fcW,
                                              const float* __restrict__ fcb,
                                              float* __restrict__ out) {
    __shared__ float lds[4][128];
    __shared__ float pcol[128];
    int g = blockIdx.x;
    int tid = threadIdx.x;
    int wid = tid >> 6, lane = tid & 63;
    int s = gstart[g], e = gstart[g + 1];
    float ax = 0.f, ay = 0.f;
    for (int n = s + wid; n < e; n += 4) {
        unsigned int v = h[(size_t)n * 64 + lane];
        ax += bf_lo(v);
        ay += bf_hi(v);
    }
    lds[wid][lane * 2] = ax;
    lds[wid][lane * 2 + 1] = ay;
    __syncthreads();
    if (tid < 128) {
        float acc = lds[0][tid] + lds[1][tid] + lds[2][tid] + lds[3][tid];
        pcol[tid] = bng[tid] * (acc - bnrm[tid]) * rsqrtf(bnrv[tid] + BN_EPS) + bnb[tid];
    }
    __syncthreads();
    if (tid < LATENT) {
        float acc = fcb[tid];
#pragma unroll 8
        for (int c = 0; c < HH; ++c) acc += pcol[c] * fcW[c * LATENT + tid];
        out[g * LATENT + tid] = acc;
    }
}

extern "C" void kernel_launch(void* const* d_in, const int* in_sizes, int n_in,
                              void* d_out, int out_size, void* d_ws, size_t ws_size,
                              hipStream_t stream) {
    const float* x = (const float*)d_in[0];
    const int* ei = (const int*)d_in[1];
    const int* batch = (const int*)d_in[2];
    const float* W1 = (const float*)d_in[3];
    const float* b1 = (const float*)d_in[4];
    const float* g1 = (const float*)d_in[5];
    const float* beta1 = (const float*)d_in[6];
    const float* rm1 = (const float*)d_in[7];
    const float* rv1 = (const float*)d_in[8];
    const float* W2 = (const float*)d_in[9];
    const float* b2 = (const float*)d_in[10];
    const float* bn_g = (const float*)d_in[11];
    const float* bn_b = (const float*)d_in[12];
    const float* bn_rm = (const float*)d_in[13];
    const float* bn_rv = (const float*)d_in[14];
    const float* fcW = (const float*)d_in[15];
    const float* fcb = (const float*)d_in[16];
    float* out = (float*)d_out;

    const int* src = ei;
    const int* dst = ei + EE;

    char* w = (char*)d_ws;
    size_t off = 0;
    auto alloc = [&](size_t bytes) -> char* {
        char* p = w + off;
        off += (bytes + 1023) & ~(size_t)1023;
        return p;
    };
    unsigned int* hx = (unsigned int*)alloc(4 * (size_t)NN * 64);
    unsigned int* ubuf = (unsigned int*)alloc(4 * (size_t)NN * 64);
    unsigned int* hbuf = (unsigned int*)alloc(4 * (size_t)NN * 64);
    uint4* Wf = (uint4*)alloc(16 * (size_t)6 * 2048);
    int* deg2 = (int*)alloc(4 * (size_t)NC);
    int* row_ptr2 = (int*)alloc(4 * (size_t)(NC + 1));
    int* rank = (int*)alloc(4 * (size_t)EE);
    int* col = (int*)alloc(4 * (size_t)EE);
    int* bsum = (int*)alloc(4 * 1024);
    int* gstart = (int*)alloc(4 * (GG + 1));
    (void)ws_size; (void)in_sizes; (void)n_in; (void)out_size;

    hipMemsetAsync(deg2, 0, 4 * (size_t)NC, stream);
    histprep<<<HP_BLOCKS, 256, 0, stream>>>(dst, deg2, rank, batch, gstart,
                                            W1, W2, Wf, (const float4*)x, (uint4*)hx);
    scan1<<<NB2, 256, 0, stream>>>(deg2, bsum);
    scan3f<<<NB2, 256, 0, stream>>>(deg2, bsum, row_ptr2);
    fill2<<<(EE + 255) / 256, 256, 0, stream>>>(src, dst, rank, row_ptr2, col);

    const int gblocks = (NN + 127) / 128;
    const unsigned int* hcur = hx;
    for (int i = 0; i < LL; ++i) {
        agg_bf16w8<<<(NN + 3) / 4, 256, 0, stream>>>(hcur, row_ptr2, col, ubuf);
        mlp_fused<<<gblocks, 256, 0, stream>>>((const unsigned short*)ubuf,
                                               Wf + (size_t)(2 * i) * 2048,
                                               Wf + (size_t)(2 * i + 1) * 2048,
                                               b1 + i * HH, g1 + i * HH, beta1 + i * HH,
                                               rm1 + i * HH, rv1 + i * HH, b2 + i * HH,
                                               (unsigned short*)hbuf);
        hcur = hbuf;
    }
    poolfc<<<GG, 256, 0, stream>>>(hbuf, gstart, bn_g, bn_b, bn_rm, bn_rv, fcW, fcb, out);
}

// Round 13
// 505.810 us; speedup vs baseline: 1.1732x; 1.1732x over previous
//
#include <hip/hip_runtime.h>

#define NN 100000
#define EE 1600000
#define DD 128
#define HH 128
#define LL 3
#define GG 512
#define LATENT 64
#define BN_EPS 1e-5f
#define SLOPE 0.2f
#define ASTR 136        // padded LDS row stride (ushorts); 272B = 17*16B (uint4-aligned)
#define NC (2 * NN)     // split counters: 2 per node
#define NB2 782         // ceil(NC/256)

typedef __attribute__((ext_vector_type(8))) short short8;
typedef __attribute__((ext_vector_type(4))) float floatx4;
typedef __attribute__((ext_vector_type(2))) float floatx2;

__device__ __forceinline__ float leaky(float t) { return t > 0.f ? t : SLOPE * t; }

__device__ __forceinline__ unsigned short f2bf(float x) {
    union { float f; unsigned int u; } v; v.f = x;
    unsigned int r = v.u + 0x7fffu + ((v.u >> 16) & 1u);
    return (unsigned short)(r >> 16);
}
__device__ __forceinline__ unsigned int pk2(float a, float b) {
    return (unsigned int)f2bf(a) | ((unsigned int)f2bf(b) << 16);
}
__device__ __forceinline__ float bf_lo(unsigned int p) {
    union { unsigned int u; float f; } v; v.u = p << 16; return v.f;
}
__device__ __forceinline__ float bf_hi(unsigned int p) {
    union { unsigned int u; float f; } v; v.u = p & 0xffff0000u; return v.f;
}
__device__ __forceinline__ floatx2 up2(unsigned int p) {
    union { unsigned int u; float f; } lo, hi;
    lo.u = p << 16; hi.u = p & 0xffff0000u;
    floatx2 r; r.x = lo.f; r.y = hi.f; return r;
}

// ---------------- merged: hist (split counters) + gstart + cvtW + cvtX ----------------
#define HIST_B 6250
#define PG 391
#define PW 48
#define PX 6250
#define HP_BLOCKS (HIST_B + PG + PW + PX)

__global__ __launch_bounds__(256) void histprep(const int* __restrict__ dst,
                                                int* __restrict__ deg2, int* __restrict__ rank,
                                                const int* __restrict__ batch, int* __restrict__ gstart,
                                                const float* __restrict__ W1, const float* __restrict__ W2,
                                                uint4* __restrict__ Wf,
                                                const float4* __restrict__ x4, uint4* __restrict__ hx4) {
    int b = blockIdx.x;
    int tid = threadIdx.x;
    if (b < HIST_B) {
        int e = b * 256 + tid;
        if (e < EE) rank[e] = atomicAdd(&deg2[(dst[e] << 1) | (e & 1)], 1);
        return;
    }
    b -= HIST_B;
    if (b < PG) {
        int n = b * 256 + tid;
        if (n >= NN) return;
        int bb = batch[n];
        int pb = (n == 0) ? -1 : batch[n - 1];
        for (int g = pb + 1; g <= bb; ++g) gstart[g] = n;
        if (n == NN - 1)
            for (int g = bb + 1; g <= GG; ++g) gstart[g] = NN;
        return;
    }
    b -= PG;
    if (b < PW) {
        int t = b * 256 + tid;  // 6*2048
        int mat = t >> 11;
        int idx = t & 2047;
        const float* W = ((mat & 1) ? W2 : W1) + (size_t)(mat >> 1) * 128 * 128;
        int lane = idx & 63;
        int tn = (idx >> 6) & 7;
        int kk = idx >> 9;
        int n = tn * 16 + (lane & 15);
        int kb = kk * 32 + (lane >> 4) * 8;
        unsigned int p[4];
#pragma unroll
        for (int jj = 0; jj < 4; ++jj)
            p[jj] = pk2(W[(kb + 2 * jj) * 128 + n], W[(kb + 2 * jj + 1) * 128 + n]);
        Wf[t] = make_uint4(p[0], p[1], p[2], p[3]);
        return;
    }
    b -= PW;
    int i = b * 256 + tid;  // uint4 index, NN*16 total
    if (i >= NN * 16) return;
    float4 p0 = x4[2 * i], p1 = x4[2 * i + 1];
    uint4 o;
    o.x = pk2(p0.x, p0.y);
    o.y = pk2(p0.z, p0.w);
    o.z = pk2(p1.x, p1.y);
    o.w = pk2(p1.z, p1.w);
    hx4[i] = o;
}

// ---------------- scan1: per-256-chunk sums of deg2 ----------------
__global__ __launch_bounds__(256) void scan1(const int* __restrict__ deg2, int* __restrict__ bsum) {
    __shared__ int lds[256];
    int n = blockIdx.x * 256 + threadIdx.x;
    lds[threadIdx.x] = (n < NC) ? deg2[n] : 0;
    __syncthreads();
    for (int off = 128; off > 0; off >>= 1) {
        if (threadIdx.x < off) lds[threadIdx.x] += lds[threadIdx.x + off];
        __syncthreads();
    }
    if (threadIdx.x == 0) bsum[blockIdx.x] = lds[0];
}

// ---------------- scan3f: block offset (reduce bsum[j<bid]) + local exclusive scan ----------------
__global__ __launch_bounds__(256) void scan3f(const int* __restrict__ deg2, const int* __restrict__ bsum,
                                              int* __restrict__ row_ptr2) {
    __shared__ int red[256];
    int tid = threadIdx.x;
    int bid = blockIdx.x;
    int acc = 0;
    for (int j = tid; j < bid; j += 256) acc += bsum[j];
    red[tid] = acc;
    __syncthreads();
    for (int off = 128; off > 0; off >>= 1) {
        if (tid < off) red[tid] += red[tid + off];
        __syncthreads();
    }
    int base = red[0];
    __syncthreads();
    int n = bid * 256 + tid;
    int v = (n < NC) ? deg2[n] : 0;
    red[tid] = v;
    __syncthreads();
    for (int off = 1; off < 256; off <<= 1) {
        int t = (tid >= off) ? red[tid - off] : 0;
        __syncthreads();
        red[tid] += t;
        __syncthreads();
    }
    if (n < NC) row_ptr2[n] = base + red[tid] - v;
    if (n == 0) row_ptr2[NC] = EE;
}

// ---------------- fill: atomic-free scatter ----------------
__global__ void fill2(const int* __restrict__ src, const int* __restrict__ dst,
                      const int* __restrict__ rank, const int* __restrict__ row_ptr2,
                      int* __restrict__ col) {
    int e = blockIdx.x * blockDim.x + threadIdx.x;
    if (e < EE) col[row_ptr2[(dst[e] << 1) | (e & 1)] + rank[e]] = src[e];
}

// ---------------- aggregation (bf16, 8 edge slots, 2 uint4/lane) ----------------
__global__ __launch_bounds__(256) void agg_bf16w8(const unsigned int* __restrict__ h,
                                                  const int* __restrict__ row_ptr2,
                                                  const int* __restrict__ col,
                                                  unsigned int* __restrict__ u) {
    int node = blockIdx.x * 4 + (threadIdx.x >> 6);
    int lane = threadIdx.x & 63;
    if (node >= NN) return;
    const int grp = lane >> 3;
    const int sub = lane & 7;
    const uint4* hv = (const uint4*)h;

    floatx2 a[8];
#pragma unroll
    for (int t = 0; t < 8; ++t) { a[t].x = 0.f; a[t].y = 0.f; }

    if (grp == 0) {
        uint4 v0 = hv[(size_t)node * 16 + sub];
        uint4 v1 = hv[(size_t)node * 16 + 8 + sub];
        a[0] += up2(v0.x); a[1] += up2(v0.y); a[2] += up2(v0.z); a[3] += up2(v0.w);
        a[4] += up2(v1.x); a[5] += up2(v1.y); a[6] += up2(v1.z); a[7] += up2(v1.w);
    }
    int s = row_ptr2[node << 1], e = row_ptr2[(node << 1) + 2];
    for (int j = s + grp; j < e; j += 8) {
        int c = col[j];
        uint4 v0 = hv[(size_t)c * 16 + sub];
        uint4 v1 = hv[(size_t)c * 16 + 8 + sub];
        a[0] += up2(v0.x); a[1] += up2(v0.y); a[2] += up2(v0.z); a[3] += up2(v0.w);
        a[4] += up2(v1.x); a[5] += up2(v1.y); a[6] += up2(v1.z); a[7] += up2(v1.w);
    }
#pragma unroll
    for (int t = 0; t < 8; ++t) {
        a[t].x += __shfl_xor(a[t].x, 8);
        a[t].y += __shfl_xor(a[t].y, 8);
        a[t].x += __shfl_xor(a[t].x, 16);
        a[t].y += __shfl_xor(a[t].y, 16);
        a[t].x += __shfl_xor(a[t].x, 32);
        a[t].y += __shfl_xor(a[t].y, 32);
    }
    if (grp == 0) {
        uint4 o0, o1;
        o0.x = pk2(a[0].x, a[0].y);
        o0.y = pk2(a[1].x, a[1].y);
        o0.z = pk2(a[2].x, a[2].y);
        o0.w = pk2(a[3].x, a[3].y);
        o1.x = pk2(a[4].x, a[4].y);
        o1.y = pk2(a[5].x, a[5].y);
        o1.z = pk2(a[6].x, a[6].y);
        o1.w = pk2(a[7].x, a[7].y);
        ((uint4*)u)[(size_t)node * 16 + sub] = o0;
        ((uint4*)u)[(size_t)node * 16 + 8 + sub] = o1;
    }
}

// ---------------- fused MLP: Out = leaky(BN(leaky(A@W1+b1))@W2 + b2) ----------------
// r10 structure (best measured): separate aL/mL buffers + barriers; epilogue 2
// stages the output tile through aL -> fully coalesced uint4 global stores.
__global__ __launch_bounds__(256) void mlp_fused(const unsigned short* __restrict__ A,
                                                 const uint4* __restrict__ W1f,
                                                 const uint4* __restrict__ W2f,
                                                 const float* __restrict__ b1,
                                                 const float* __restrict__ g,
                                                 const float* __restrict__ beta,
                                                 const float* __restrict__ rm,
                                                 const float* __restrict__ rv,
                                                 const float* __restrict__ b2,
                                                 unsigned short* __restrict__ Out) {
    __shared__ unsigned short aL[128 * ASTR];
    __shared__ unsigned short mL[4][32 * ASTR];
    const int tid = threadIdx.x;
    const int rb = blockIdx.x * 128;

    const uint4* Ag = (const uint4*)(A + (size_t)rb * 128);
#pragma unroll
    for (int it = 0; it < 8; ++it) {
        int idx = it * 256 + tid;
        int r = idx >> 4, c = idx & 15;
        uint4 v = make_uint4(0u, 0u, 0u, 0u);
        if (rb + r < NN) v = Ag[idx];
        *(uint4*)&aL[r * ASTR + c * 8] = v;
    }
    __syncthreads();

    const int wid = tid >> 6, lane = tid & 63;
    const int ml = lane & 15, q = lane >> 4;
    const int m0 = wid * 32;

    floatx4 acc[2][8] = {};
#pragma unroll
    for (int kk = 0; kk < 4; ++kk) {
        short8 af[2];
#pragma unroll
        for (int t = 0; t < 2; ++t)
            af[t] = *(const short8*)&aL[(m0 + t * 16 + ml) * ASTR + kk * 32 + q * 8];
#pragma unroll
        for (int tn = 0; tn < 8; ++tn) {
            uint4 bq = W1f[(kk * 8 + tn) * 64 + lane];
            short8 bf = *(short8*)&bq;
            acc[0][tn] = __builtin_amdgcn_mfma_f32_16x16x32_bf16(af[0], bf, acc[0][tn], 0, 0, 0);
            acc[1][tn] = __builtin_amdgcn_mfma_f32_16x16x32_bf16(af[1], bf, acc[1][tn], 0, 0, 0);
        }
    }

    // epilogue 1: bias + leaky + BN -> per-wave LDS mid (bf16)
#pragma unroll
    for (int tn = 0; tn < 8; ++tn) {
        int c = tn * 16 + ml;
        float s = g[c] * rsqrtf(rv[c] + BN_EPS);
        float sh = beta[c] - s * rm[c];
        float bv = b1[c];
#pragma unroll
        for (int t = 0; t < 2; ++t)
#pragma unroll
            for (int r = 0; r < 4; ++r) {
                float val = leaky(acc[t][tn][r] + bv);
                val = s * val + sh;
                mL[wid][(t * 16 + q * 4 + r) * ASTR + c] = f2bf(val);
            }
    }
    __syncthreads();

    floatx4 acc2[2][8] = {};
#pragma unroll
    for (int kk = 0; kk < 4; ++kk) {
        short8 af[2];
#pragma unroll
        for (int t = 0; t < 2; ++t)
            af[t] = *(const short8*)&mL[wid][(t * 16 + ml) * ASTR + kk * 32 + q * 8];
#pragma unroll
        for (int tn = 0; tn < 8; ++tn) {
            uint4 bq = W2f[(kk * 8 + tn) * 64 + lane];
            short8 bf = *(short8*)&bq;
            acc2[0][tn] = __builtin_amdgcn_mfma_f32_16x16x32_bf16(af[0], bf, acc2[0][tn], 0, 0, 0);
            acc2[1][tn] = __builtin_amdgcn_mfma_f32_16x16x32_bf16(af[1], bf, acc2[1][tn], 0, 0, 0);
        }
    }

    // epilogue 2: bias + leaky -> aL (reused), then coalesced vector stores
#pragma unroll
    for (int tn = 0; tn < 8; ++tn) {
        int c = tn * 16 + ml;
        float bv = b2[c];
#pragma unroll
        for (int t = 0; t < 2; ++t)
#pragma unroll
            for (int r = 0; r < 4; ++r)
                aL[(m0 + t * 16 + q * 4 + r) * ASTR + c] = f2bf(leaky(acc2[t][tn][r] + bv));
    }
    __syncthreads();

    uint4* Og = (uint4*)(Out + (size_t)rb * 128);
#pragma unroll
    for (int it = 0; it < 8; ++it) {
        int idx = it * 256 + tid;
        int r = idx >> 4, c = idx & 15;
        if (rb + r < NN)
            Og[idx] = *(const uint4*)&aL[r * ASTR + c * 8];
    }
}

// ---------------- fused pooling + BN + final FC ----------------
__global__ __launch_bounds__(256) void poolfc(const unsigned int* __restrict__ h,
                                              const int* __restrict__ gstart,
                                              const float* __restrict__ bng,
                                              const float* __restrict__ bnb,
                                              const float* __restrict__ bnrm,
                                              const float* __restrict__ bnrv,
                                              const float* __restrict__ fcW,
                                              const float* __restrict__ fcb,
                                              float* __restrict__ out) {
    __shared__ float lds[4][128];
    __shared__ float pcol[128];
    int g = blockIdx.x;
    int tid = threadIdx.x;
    int wid = tid >> 6, lane = tid & 63;
    int s = gstart[g], e = gstart[g + 1];
    float ax = 0.f, ay = 0.f;
    for (int n = s + wid; n < e; n += 4) {
        unsigned int v = h[(size_t)n * 64 + lane];
        ax += bf_lo(v);
        ay += bf_hi(v);
    }
    lds[wid][lane * 2] = ax;
    lds[wid][lane * 2 + 1] = ay;
    __syncthreads();
    if (tid < 128) {
        float acc = lds[0][tid] + lds[1][tid] + lds[2][tid] + lds[3][tid];
        pcol[tid] = bng[tid] * (acc - bnrm[tid]) * rsqrtf(bnrv[tid] + BN_EPS) + bnb[tid];
    }
    __syncthreads();
    if (tid < LATENT) {
        float acc = fcb[tid];
#pragma unroll 8
        for (int c = 0; c < HH; ++c) acc += pcol[c] * fcW[c * LATENT + tid];
        out[g * LATENT + tid] = acc;
    }
}

extern "C" void kernel_launch(void* const* d_in, const int* in_sizes, int n_in,
                              void* d_out, int out_size, void* d_ws, size_t ws_size,
                              hipStream_t stream) {
    const float* x = (const float*)d_in[0];
    const int* ei = (const int*)d_in[1];
    const int* batch = (const int*)d_in[2];
    const float* W1 = (const float*)d_in[3];
    const float* b1 = (const float*)d_in[4];
    const float* g1 = (const float*)d_in[5];
    const float* beta1 = (const float*)d_in[6];
    const float* rm1 = (const float*)d_in[7];
    const float* rv1 = (const float*)d_in[8];
    const float* W2 = (const float*)d_in[9];
    const float* b2 = (const float*)d_in[10];
    const float* bn_g = (const float*)d_in[11];
    const float* bn_b = (const float*)d_in[12];
    const float* bn_rm = (const float*)d_in[13];
    const float* bn_rv = (const float*)d_in[14];
    const float* fcW = (const float*)d_in[15];
    const float* fcb = (const float*)d_in[16];
    float* out = (float*)d_out;

    const int* src = ei;
    const int* dst = ei + EE;

    char* w = (char*)d_ws;
    size_t off = 0;
    auto alloc = [&](size_t bytes) -> char* {
        char* p = w + off;
        off += (bytes + 1023) & ~(size_t)1023;
        return p;
    };
    unsigned int* hx = (unsigned int*)alloc(4 * (size_t)NN * 64);
    unsigned int* ubuf = (unsigned int*)alloc(4 * (size_t)NN * 64);
    unsigned int* hbuf = (unsigned int*)alloc(4 * (size_t)NN * 64);
    uint4* Wf = (uint4*)alloc(16 * (size_t)6 * 2048);
    int* deg2 = (int*)alloc(4 * (size_t)NC);
    int* row_ptr2 = (int*)alloc(4 * (size_t)(NC + 1));
    int* rank = (int*)alloc(4 * (size_t)EE);
    int* col = (int*)alloc(4 * (size_t)EE);
    int* bsum = (int*)alloc(4 * 1024);
    int* gstart = (int*)alloc(4 * (GG + 1));
    (void)ws_size; (void)in_sizes; (void)n_in; (void)out_size;

    hipMemsetAsync(deg2, 0, 4 * (size_t)NC, stream);
    histprep<<<HP_BLOCKS, 256, 0, stream>>>(dst, deg2, rank, batch, gstart,
                                            W1, W2, Wf, (const float4*)x, (uint4*)hx);
    scan1<<<NB2, 256, 0, stream>>>(deg2, bsum);
    scan3f<<<NB2, 256, 0, stream>>>(deg2, bsum, row_ptr2);
    fill2<<<(EE + 255) / 256, 256, 0, stream>>>(src, dst, rank, row_ptr2, col);

    const int gblocks = (NN + 127) / 128;
    const unsigned int* hcur = hx;
    for (int i = 0; i < LL; ++i) {
        agg_bf16w8<<<(NN + 3) / 4, 256, 0, stream>>>(hcur, row_ptr2, col, ubuf);
        mlp_fused<<<gblocks, 256, 0, stream>>>((const unsigned short*)ubuf,
                                               Wf + (size_t)(2 * i) * 2048,
                                               Wf + (size_t)(2 * i + 1) * 2048,
                                               b1 + i * HH, g1 + i * HH, beta1 + i * HH,
                                               rm1 + i * HH, rv1 + i * HH, b2 + i * HH,
                                               (unsigned short*)hbuf);
        hcur = hbuf;
    }
    poolfc<<<GG, 256, 0, stream>>>(hbuf, gstart, bn_g, bn_b, bn_rm, bn_rv, fcW, fcb, out);
}